// Round 1
// baseline (16002.917 us; speedup 1.0000x reference)
//
#include <hip/hip_runtime.h>

namespace {
constexpr int kH = 512, kD = 256, kO = 256, kB = 32, kT = 2048;
constexpr int kRows = kB * kT;  // 65536
}

// ---------------- prep: W (transposed), W_in^T, W_out^T ----------------
__global__ __launch_bounds__(256) void prep_kernel(
    const float* __restrict__ S, const float* __restrict__ A,
    const float* __restrict__ lam_raw, const float* __restrict__ W_in,
    const float* __restrict__ W_out, float* __restrict__ Wt,
    float* __restrict__ W_in_t, float* __restrict__ Wout_t) {
  const int idx = blockIdx.x * 256 + threadIdx.x;
  const float lam = 1.0f / (1.0f + __expf(-lam_raw[0]));
  if (idx < kH * kH) {
    // Wt[k][j] = W[j][k]; W = lam*0.5*(S+S^T) + (1-lam)*0.5*(A-A^T)
    const int k = idx >> 9, j = idx & (kH - 1);
    const float sym = 0.5f * (S[j * kH + k] + S[k * kH + j]);
    const float asym = 0.5f * (A[j * kH + k] - A[k * kH + j]);
    Wt[idx] = lam * sym + (1.0f - lam) * asym;
  }
  if (idx < kD * kH) {  // W_in_t[d][h] = W_in[h][d]
    const int d = idx >> 9, h = idx & (kH - 1);
    W_in_t[idx] = W_in[h * kD + d];
  }
  if (idx < kH * kO) {  // Wout_t[h][o] = W_out[o][h]
    const int h = idx >> 8, o = idx & (kO - 1);
    Wout_t[idx] = W_out[o * kH + h];
  }
}

// ---------------- fp32 tiled GEMM: C[M][N] = A[M][K] @ Bt[K][N] + bias ----------------
// BM=128, BN=64, BK=16; 256 threads; 8x4 micro-tile per thread.
template <int BM, int BN, int BK>
__global__ __launch_bounds__(256) void gemm_bias_kernel(
    const float* __restrict__ A, const float* __restrict__ Bt,
    const float* __restrict__ bias, float* __restrict__ C,
    int M, int N, int K) {
  __shared__ float As[BK][BM + 4];  // +4 pad: breaks 4-way bank conflict on transposed store
  __shared__ float Bs[BK][BN];
  const int tid = threadIdx.x;
  const int m0 = blockIdx.x * BM, n0 = blockIdx.y * BN;
  const int ar = tid >> 2, ac = (tid & 3) << 2;   // A staging: 2 rows x float4
  const int br = tid >> 4, bc = (tid & 15) << 2;  // B staging: 1 float4
  const int tx = tid & 15, ty = tid >> 4;         // compute mapping
  float4 acc[8];
#pragma unroll
  for (int i = 0; i < 8; ++i) acc[i] = make_float4(0.f, 0.f, 0.f, 0.f);

  for (int k0 = 0; k0 < K; k0 += BK) {
    const float4 a0 = *(const float4*)&A[(long)(m0 + ar) * K + k0 + ac];
    const float4 a1 = *(const float4*)&A[(long)(m0 + ar + 64) * K + k0 + ac];
    const float4 b0 = *(const float4*)&Bt[(long)(k0 + br) * N + n0 + bc];
    __syncthreads();  // previous tile's compute done before LDS overwrite
    As[ac + 0][ar] = a0.x; As[ac + 1][ar] = a0.y;
    As[ac + 2][ar] = a0.z; As[ac + 3][ar] = a0.w;
    As[ac + 0][ar + 64] = a1.x; As[ac + 1][ar + 64] = a1.y;
    As[ac + 2][ar + 64] = a1.z; As[ac + 3][ar + 64] = a1.w;
    *(float4*)&Bs[br][bc] = b0;
    __syncthreads();
#pragma unroll
    for (int kk = 0; kk < BK; ++kk) {
      const float4 b4 = *(const float4*)&Bs[kk][tx * 4];
      const float4 va0 = *(const float4*)&As[kk][ty * 8];
      const float4 va1 = *(const float4*)&As[kk][ty * 8 + 4];
#define FMA_ROW(ACC, SV)                                                   \
      ACC.x += (SV) * b4.x; ACC.y += (SV) * b4.y;                          \
      ACC.z += (SV) * b4.z; ACC.w += (SV) * b4.w;
      FMA_ROW(acc[0], va0.x) FMA_ROW(acc[1], va0.y)
      FMA_ROW(acc[2], va0.z) FMA_ROW(acc[3], va0.w)
      FMA_ROW(acc[4], va1.x) FMA_ROW(acc[5], va1.y)
      FMA_ROW(acc[6], va1.z) FMA_ROW(acc[7], va1.w)
#undef FMA_ROW
    }
  }
  const float4 bv = *(const float4*)&bias[n0 + tx * 4];
#pragma unroll
  for (int mi = 0; mi < 8; ++mi) {
    float4 r;
    r.x = acc[mi].x + bv.x; r.y = acc[mi].y + bv.y;
    r.z = acc[mi].z + bv.z; r.w = acc[mi].w + bv.w;
    *(float4*)&C[(long)(m0 + ty * 8 + mi) * N + n0 + tx * 4] = r;
  }
}

// ---------------- recurrence: h_t = tanh(xp_t + W h_{t-1}), in-place over xp ----------------
// 1 block per batch, 512 threads = 8 waves. Wave e owns k-range [64e,64e+64);
// lane i owns outputs 8i..8i+7. Partials reduced through LDS. 2 barriers/step.
__global__ __launch_bounds__(512, 1) void rnn_kernel(
    const float* __restrict__ Wt, const float* __restrict__ h0,
    float* __restrict__ hs) {
  const int b = blockIdx.x;
  const int tid = threadIdx.x;
  const int i = tid & 63;
  const int e = tid >> 6;
  __shared__ float hsm[kH];
  __shared__ float part[8 * kH];
  float* hb = hs + (long)b * kT * kH;  // region pre-filled with xp by gemm
  hsm[tid] = h0[b * kH + tid];
  float xp_cur = hb[tid];  // xp row 0
  __syncthreads();
  const float4* W4base = (const float4*)Wt + e * (64 * (kH / 4)) + 2 * i;
  for (int t = 0; t < kT; ++t) {
    const int tn = (t + 1 < kT) ? (t + 1) : (kT - 1);
    const float xp_next = hb[(long)tn * kH + tid];  // issued early: k-loop hides HBM latency
    float4 acc0 = make_float4(0.f, 0.f, 0.f, 0.f);
    float4 acc1 = make_float4(0.f, 0.f, 0.f, 0.f);
    const float4* wp = W4base;
    const float* hp = &hsm[64 * e];
#pragma unroll 8
    for (int k = 0; k < 64; ++k) {
      const float hk = hp[k];           // LDS broadcast (wave-uniform)
      const float4 w0 = wp[0];          // coalesced 2KB/row across wave
      const float4 w1 = wp[1];
      acc0.x += w0.x * hk; acc0.y += w0.y * hk;
      acc0.z += w0.z * hk; acc0.w += w0.w * hk;
      acc1.x += w1.x * hk; acc1.y += w1.y * hk;
      acc1.z += w1.z * hk; acc1.w += w1.w * hk;
      wp += (kH / 4);
    }
    *(float4*)&part[e * kH + 8 * i] = acc0;
    *(float4*)&part[e * kH + 8 * i + 4] = acc1;
    __syncthreads();
    float s = xp_cur;
#pragma unroll
    for (int ee = 0; ee < 8; ++ee) s += part[ee * kH + tid];
    const float hn = tanhf(s);
    hb[(long)t * kH + tid] = hn;  // overwrite xp row t with h_t (coalesced)
    hsm[tid] = hn;
    xp_cur = xp_next;
    __syncthreads();
  }
}

// ---------------- in-place row softmax (rows of 256), one wave per row ----------------
__global__ __launch_bounds__(256) void softmax_kernel(float* __restrict__ Z) {
  const int lane = threadIdx.x & 63;
  const int wid = threadIdx.x >> 6;
  const long row = (long)blockIdx.x * 4 + wid;
  float* z = Z + row * kO;
  float4 v = *(float4*)&z[lane * 4];
  float m = fmaxf(fmaxf(v.x, v.y), fmaxf(v.z, v.w));
#pragma unroll
  for (int off = 32; off > 0; off >>= 1) m = fmaxf(m, __shfl_xor(m, off));
  v.x = __expf(v.x - m); v.y = __expf(v.y - m);
  v.z = __expf(v.z - m); v.w = __expf(v.w - m);
  float ssum = v.x + v.y + v.z + v.w;
#pragma unroll
  for (int off = 32; off > 0; off >>= 1) ssum += __shfl_xor(ssum, off);
  const float r = 1.0f / ssum;
  v.x *= r; v.y *= r; v.z *= r; v.w *= r;
  *(float4*)&z[lane * 4] = v;
}

extern "C" void kernel_launch(void* const* d_in, const int* in_sizes, int n_in,
                              void* d_out, int out_size, void* d_ws, size_t ws_size,
                              hipStream_t stream) {
  const float* x     = (const float*)d_in[0];
  const float* h0    = (const float*)d_in[1];
  const float* S     = (const float*)d_in[2];
  const float* A     = (const float*)d_in[3];
  const float* lam   = (const float*)d_in[4];
  const float* W_in  = (const float*)d_in[5];
  const float* b_in  = (const float*)d_in[6];
  const float* W_out = (const float*)d_in[7];
  const float* b_out = (const float*)d_in[8];

  float* ys = (float*)d_out;                  // [B,T,O]
  float* hs = ys + (long)kB * kT * kO;        // [B,T,H] — doubles as xp scratch

  float* Wt     = (float*)d_ws;               // 512*512
  float* W_in_t = Wt + kH * kH;               // 256*512
  float* Wout_t = W_in_t + kD * kH;           // 512*256  (total 2MB of d_ws)

  prep_kernel<<<1024, 256, 0, stream>>>(S, A, lam, W_in, W_out, Wt, W_in_t, Wout_t);

  // xp = x @ W_in^T + b_in  -> into hs region
  dim3 g2(kRows / 128, kH / 64);
  gemm_bias_kernel<128, 64, 16><<<g2, 256, 0, stream>>>(x, W_in_t, b_in, hs,
                                                        kRows, kH, kD);
  // sequential scan, in-place xp -> h
  rnn_kernel<<<kB, 512, 0, stream>>>(Wt, h0, hs);

  // logits = hs @ W_out^T + b_out -> into ys region
  dim3 g4(kRows / 128, kO / 64);
  gemm_bias_kernel<128, 64, 16><<<g4, 256, 0, stream>>>(hs, Wout_t, b_out, ys,
                                                        kRows, kO, kH);
  // softmax in place
  softmax_kernel<<<kRows / 4, 256, 0, stream>>>(ys);
}

// Round 2
// 3703.956 us; speedup vs baseline: 4.3205x; 4.3205x over previous
//
#include <hip/hip_runtime.h>

namespace {
constexpr int kH = 512, kD = 256, kO = 256, kB = 32, kT = 2048;
constexpr int kRows = kB * kT;  // 65536
constexpr int kSlices = 8;      // blocks per batch (8 * 32 = 256 blocks = 256 CUs)
}

// ---------------- prep: W (transposed), W_in^T, W_out^T ----------------
__global__ __launch_bounds__(256) void prep_kernel(
    const float* __restrict__ S, const float* __restrict__ A,
    const float* __restrict__ lam_raw, const float* __restrict__ W_in,
    const float* __restrict__ W_out, float* __restrict__ Wt,
    float* __restrict__ W_in_t, float* __restrict__ Wout_t) {
  const int idx = blockIdx.x * 256 + threadIdx.x;
  const float lam = 1.0f / (1.0f + __expf(-lam_raw[0]));
  if (idx < kH * kH) {
    // Wt[k][j] = W[j][k]; W = lam*0.5*(S+S^T) + (1-lam)*0.5*(A-A^T)
    const int k = idx >> 9, j = idx & (kH - 1);
    const float sym = 0.5f * (S[j * kH + k] + S[k * kH + j]);
    const float asym = 0.5f * (A[j * kH + k] - A[k * kH + j]);
    Wt[idx] = lam * sym + (1.0f - lam) * asym;
  }
  if (idx < kD * kH) {  // W_in_t[d][h] = W_in[h][d]
    const int d = idx >> 9, h = idx & (kH - 1);
    W_in_t[idx] = W_in[h * kD + d];
  }
  if (idx < kH * kO) {  // Wout_t[h][o] = W_out[o][h]
    const int h = idx >> 8, o = idx & (kO - 1);
    Wout_t[idx] = W_out[o * kH + h];
  }
}

// ---------------- fp32 tiled GEMM: C[M][N] = A[M][K] @ Bt[K][N] + bias ----------------
template <int BM, int BN, int BK>
__global__ __launch_bounds__(256) void gemm_bias_kernel(
    const float* __restrict__ A, const float* __restrict__ Bt,
    const float* __restrict__ bias, float* __restrict__ C,
    int M, int N, int K) {
  __shared__ float As[BK][BM + 4];
  __shared__ float Bs[BK][BN];
  const int tid = threadIdx.x;
  const int m0 = blockIdx.x * BM, n0 = blockIdx.y * BN;
  const int ar = tid >> 2, ac = (tid & 3) << 2;
  const int br = tid >> 4, bc = (tid & 15) << 2;
  const int tx = tid & 15, ty = tid >> 4;
  float4 acc[8];
#pragma unroll
  for (int i = 0; i < 8; ++i) acc[i] = make_float4(0.f, 0.f, 0.f, 0.f);

  for (int k0 = 0; k0 < K; k0 += BK) {
    const float4 a0 = *(const float4*)&A[(long)(m0 + ar) * K + k0 + ac];
    const float4 a1 = *(const float4*)&A[(long)(m0 + ar + 64) * K + k0 + ac];
    const float4 b0 = *(const float4*)&Bt[(long)(k0 + br) * N + n0 + bc];
    __syncthreads();
    As[ac + 0][ar] = a0.x; As[ac + 1][ar] = a0.y;
    As[ac + 2][ar] = a0.z; As[ac + 3][ar] = a0.w;
    As[ac + 0][ar + 64] = a1.x; As[ac + 1][ar + 64] = a1.y;
    As[ac + 2][ar + 64] = a1.z; As[ac + 3][ar + 64] = a1.w;
    *(float4*)&Bs[br][bc] = b0;
    __syncthreads();
#pragma unroll
    for (int kk = 0; kk < BK; ++kk) {
      const float4 b4 = *(const float4*)&Bs[kk][tx * 4];
      const float4 va0 = *(const float4*)&As[kk][ty * 8];
      const float4 va1 = *(const float4*)&As[kk][ty * 8 + 4];
#define FMA_ROW(ACC, SV)                                                   \
      ACC.x += (SV) * b4.x; ACC.y += (SV) * b4.y;                          \
      ACC.z += (SV) * b4.z; ACC.w += (SV) * b4.w;
      FMA_ROW(acc[0], va0.x) FMA_ROW(acc[1], va0.y)
      FMA_ROW(acc[2], va0.z) FMA_ROW(acc[3], va0.w)
      FMA_ROW(acc[4], va1.x) FMA_ROW(acc[5], va1.y)
      FMA_ROW(acc[6], va1.z) FMA_ROW(acc[7], va1.w)
#undef FMA_ROW
    }
  }
  const float4 bv = *(const float4*)&bias[n0 + tx * 4];
#pragma unroll
  for (int mi = 0; mi < 8; ++mi) {
    float4 r;
    r.x = acc[mi].x + bv.x; r.y = acc[mi].y + bv.y;
    r.z = acc[mi].z + bv.z; r.w = acc[mi].w + bv.w;
    *(float4*)&C[(long)(m0 + ty * 8 + mi) * N + n0 + tx * 4] = r;
  }
}

// ---------------- recurrence, W register-resident, 8 blocks per batch ----------------
// Block (b, s) owns outputs jg in [64s, 64s+64) of batch b. 512 threads = 8 waves;
// wave kc covers k-range [64kc, 64kc+64); lane j pairs with output 64s+j.
// W slice lives in 64 VGPRs/thread (loaded once). Per step, h is exchanged between
// the 8 sibling blocks via 8-byte agent-scope atomics packing (seq<<32 | h_bits):
// data + readiness travel in ONE word -> one L3 round trip per step. Slots are
// double-buffered by step parity; a producer can run at most 2 steps ahead of the
// slowest sibling before its next overwrite, which the poll handshake prevents
// from clobbering unread data (overwrite of seq t+1 data requires everyone
// consumed it -- see poll condition seq == t exactly).
__global__ __launch_bounds__(512, 1) void rnn_kernel(
    const float* __restrict__ Wt, const float* __restrict__ h0,
    float* __restrict__ hs, unsigned long long* __restrict__ hglob) {
  const int bid = blockIdx.x;
  const int b = bid >> 3;
  const int s = bid & 7;
  const int tid = threadIdx.x;
  const int j = tid & 63;
  const int kc = tid >> 6;
  const int jg = s * 64 + j;
  __shared__ float h_lds[kH];
  __shared__ float part[8 * 64];  // [kc][j] -> banks j%32, 2-way = free

  // One-time: W slice into registers. wk[m] = Wt[64*kc + m][jg] = W[jg][64*kc+m]
  float wk[64];
  const float* wp = Wt + (long)(64 * kc) * kH + jg;
#pragma unroll
  for (int m = 0; m < 64; ++m) wk[m] = wp[(long)m * kH];

  float* hb = hs + (long)b * kT * kH;               // pre-filled with xp
  unsigned long long* hg = hglob + (long)b * 1024;  // [2 slots][512]

  for (int t = 0; t < kT; ++t) {
    // issue xp load early (only wave 0 consumes it, after the reduce)
    float xpv = 0.f;
    if (kc == 0) xpv = hb[(long)t * kH + jg];

    // stage h_{t} into LDS: thread tid owns k = tid
    if (t == 0) {
      h_lds[tid] = h0[b * kH + tid];
    } else {
      const int slot = t & 1;
      unsigned long long v;
      do {
        v = __hip_atomic_load(&hg[slot * 512 + tid], __ATOMIC_RELAXED,
                              __HIP_MEMORY_SCOPE_AGENT);
      } while ((unsigned)(v >> 32) != (unsigned)t);
      h_lds[tid] = __uint_as_float((unsigned)v);
    }
    __syncthreads();

    // partial dot over this wave's k-chunk (h_lds reads are wave-uniform b128)
    const float4* h4 = (const float4*)&h_lds[64 * kc];
    float a0 = 0.f, a1 = 0.f, a2 = 0.f, a3 = 0.f;
#pragma unroll
    for (int q = 0; q < 16; ++q) {
      const float4 hv = h4[q];
      a0 += wk[4 * q + 0] * hv.x;
      a1 += wk[4 * q + 1] * hv.y;
      a2 += wk[4 * q + 2] * hv.z;
      a3 += wk[4 * q + 3] * hv.w;
    }
    part[kc * 64 + j] = (a0 + a1) + (a2 + a3);
    __syncthreads();

    if (kc == 0) {
      float sum = xpv;
#pragma unroll
      for (int e = 0; e < 8; ++e) sum += part[e * 64 + j];
      const float hn = tanhf(sum);
      hb[(long)t * kH + jg] = hn;  // output h_t (overwrites consumed xp)
      const unsigned long long pv =
          ((unsigned long long)(unsigned)(t + 1) << 32) | __float_as_uint(hn);
      __hip_atomic_store(&hg[((t + 1) & 1) * 512 + jg], pv, __ATOMIC_RELAXED,
                         __HIP_MEMORY_SCOPE_AGENT);
    }
    // waves kc>0 run ahead to the next poll; LDS hazards are covered by the
    // two barriers above (wave 0 only touches part[]/xp/global after B2).
  }
}

// ---------------- in-place row softmax (rows of 256), one wave per row ----------------
__global__ __launch_bounds__(256) void softmax_kernel(float* __restrict__ Z) {
  const int lane = threadIdx.x & 63;
  const int wid = threadIdx.x >> 6;
  const long row = (long)blockIdx.x * 4 + wid;
  float* z = Z + row * kO;
  float4 v = *(float4*)&z[lane * 4];
  float m = fmaxf(fmaxf(v.x, v.y), fmaxf(v.z, v.w));
#pragma unroll
  for (int off = 32; off > 0; off >>= 1) m = fmaxf(m, __shfl_xor(m, off));
  v.x = __expf(v.x - m); v.y = __expf(v.y - m);
  v.z = __expf(v.z - m); v.w = __expf(v.w - m);
  float ssum = v.x + v.y + v.z + v.w;
#pragma unroll
  for (int off = 32; off > 0; off >>= 1) ssum += __shfl_xor(ssum, off);
  const float r = 1.0f / ssum;
  v.x *= r; v.y *= r; v.z *= r; v.w *= r;
  *(float4*)&z[lane * 4] = v;
}

extern "C" void kernel_launch(void* const* d_in, const int* in_sizes, int n_in,
                              void* d_out, int out_size, void* d_ws, size_t ws_size,
                              hipStream_t stream) {
  const float* x     = (const float*)d_in[0];
  const float* h0    = (const float*)d_in[1];
  const float* S     = (const float*)d_in[2];
  const float* A     = (const float*)d_in[3];
  const float* lam   = (const float*)d_in[4];
  const float* W_in  = (const float*)d_in[5];
  const float* b_in  = (const float*)d_in[6];
  const float* W_out = (const float*)d_in[7];
  const float* b_out = (const float*)d_in[8];

  float* ys = (float*)d_out;                  // [B,T,O]
  float* hs = ys + (long)kB * kT * kO;        // [B,T,H] — doubles as xp scratch

  float* Wt     = (float*)d_ws;               // 512*512 fp32 = 1MB
  float* W_in_t = Wt + kH * kH;               // 256*512 fp32 = 512KB
  float* Wout_t = W_in_t + kD * kH;           // 512*256 fp32 = 512KB (total 2MB)
  // hglob (32*2*512*8B = 256KB) ALIASES the W_in_t region: W_in_t is only read
  // by gemm1, which completes (stream order) before rnn_kernel's first write.
  // Leftover W_in_t float bit-patterns in the seq word can never equal a live
  // seq value 1..2048 (those are denormal bit patterns; weights are normal
  // floats or exact 0), and 0xAA poison can't either.
  unsigned long long* hglob = (unsigned long long*)W_in_t;

  prep_kernel<<<1024, 256, 0, stream>>>(S, A, lam, W_in, W_out, Wt, W_in_t, Wout_t);

  // xp = x @ W_in^T + b_in  -> into hs region
  dim3 g2(kRows / 128, kH / 64);
  gemm_bias_kernel<128, 64, 16><<<g2, 256, 0, stream>>>(x, W_in_t, b_in, hs,
                                                        kRows, kH, kD);
  // sequential scan: 8 blocks per batch, W in registers, h exchanged via L3 atomics
  rnn_kernel<<<kB * kSlices, 512, 0, stream>>>(Wt, h0, hs, hglob);

  // logits = hs @ W_out^T + b_out -> into ys region
  dim3 g4(kRows / 128, kO / 64);
  gemm_bias_kernel<128, 64, 16><<<g4, 256, 0, stream>>>(hs, Wout_t, b_out, ys,
                                                        kRows, kO, kH);
  // softmax in place
  softmax_kernel<<<kRows / 4, 256, 0, stream>>>(ys);
}